// Round 1
// baseline (1379.457 us; speedup 1.0000x reference)
//
#include <hip/hip_runtime.h>
#include <math.h>

#define NNODES 50000
#define NEDGES 1600000
#define DOUT 256
#define NEG_SLOPE 0.2f

__device__ __forceinline__ float lrelu(float e) { return e > 0.f ? e : NEG_SLOPE * e; }

// ---------------- CSR build ----------------
__global__ void k_hist(const int* __restrict__ ei, int* __restrict__ deg) {
  int e = blockIdx.x * 256 + threadIdx.x;
  const int EP = NEDGES + NNODES;
  if (e >= EP) return;
  int dst = (e < NEDGES) ? ei[NEDGES + e] : (e - NEDGES);
  atomicAdd(&deg[dst], 1);
}

__global__ void k_scan(const int* __restrict__ deg, int* __restrict__ rowptr) {
  __shared__ int wsum[4];
  const int t = threadIdx.x, lane = t & 63, w = t >> 6;
  int carry = 0;
  for (int base = 0; base < NNODES; base += 256) {
    int i = base + t;
    int x = (i < NNODES) ? deg[i] : 0;
    #pragma unroll
    for (int off = 1; off < 64; off <<= 1) {
      int y = __shfl_up(x, off);
      if (lane >= off) x += y;
    }
    if (lane == 63) wsum[w] = x;
    __syncthreads();
    int s0 = wsum[0], s1 = wsum[1], s2 = wsum[2], s3 = wsum[3];
    int woff = (w > 0 ? s0 : 0) + (w > 1 ? s1 : 0) + (w > 2 ? s2 : 0);
    if (i < NNODES) rowptr[i + 1] = carry + woff + x;
    carry += s0 + s1 + s2 + s3;
    __syncthreads();
  }
  if (t == 0) rowptr[0] = 0;
}

__global__ void k_scatter(const int* __restrict__ ei, const int* __restrict__ rowptr,
                          int* __restrict__ fill, int* __restrict__ esrc) {
  int e = blockIdx.x * 256 + threadIdx.x;
  const int EP = NEDGES + NNODES;
  if (e >= EP) return;
  int src, dst;
  if (e < NEDGES) { src = ei[e]; dst = ei[NEDGES + e]; }
  else            { src = e - NEDGES; dst = src; }
  int pos = rowptr[dst] + atomicAdd(&fill[dst], 1);
  esrc[pos] = src;
}

// ---------------- GEMM (h = A @ W) + fused attention logits ----------------
// block 256 = 4 waves; wave handles 16 rows, lane handles 4 consecutive cols.
template<int DIN>
__global__ __launch_bounds__(256) void k_gemm_attn(
    const float* __restrict__ A, const float* __restrict__ W,
    const float* __restrict__ a_src, const float* __restrict__ a_dst,
    float* __restrict__ H, float* __restrict__ asn, float* __restrict__ adn)
{
  const int lane = threadIdx.x & 63;
  const int wv = __builtin_amdgcn_readfirstlane(threadIdx.x >> 6);
  const int row0 = blockIdx.x * 64 + wv * 16;

  const float4* __restrict__ Bv = reinterpret_cast<const float4*>(W);
  const float* Arow[16];
  #pragma unroll
  for (int r = 0; r < 16; ++r) {
    int row = row0 + r; if (row >= NNODES) row = NNODES - 1;
    Arow[r] = A + (size_t)row * DIN;
  }
  float4 acc[16];
  #pragma unroll
  for (int r = 0; r < 16; ++r) acc[r] = make_float4(0.f, 0.f, 0.f, 0.f);

  for (int k = 0; k < DIN; k += 4) {
    float4 b0 = Bv[(size_t)(k + 0) * 64 + lane];
    float4 b1 = Bv[(size_t)(k + 1) * 64 + lane];
    float4 b2 = Bv[(size_t)(k + 2) * 64 + lane];
    float4 b3 = Bv[(size_t)(k + 3) * 64 + lane];
    #pragma unroll
    for (int r = 0; r < 16; ++r) {
      const float4 av = *reinterpret_cast<const float4*>(Arow[r] + k);
      acc[r].x = fmaf(av.x, b0.x, acc[r].x); acc[r].y = fmaf(av.x, b0.y, acc[r].y);
      acc[r].z = fmaf(av.x, b0.z, acc[r].z); acc[r].w = fmaf(av.x, b0.w, acc[r].w);
      acc[r].x = fmaf(av.y, b1.x, acc[r].x); acc[r].y = fmaf(av.y, b1.y, acc[r].y);
      acc[r].z = fmaf(av.y, b1.z, acc[r].z); acc[r].w = fmaf(av.y, b1.w, acc[r].w);
      acc[r].x = fmaf(av.z, b2.x, acc[r].x); acc[r].y = fmaf(av.z, b2.y, acc[r].y);
      acc[r].z = fmaf(av.z, b2.z, acc[r].z); acc[r].w = fmaf(av.z, b2.w, acc[r].w);
      acc[r].x = fmaf(av.w, b3.x, acc[r].x); acc[r].y = fmaf(av.w, b3.y, acc[r].y);
      acc[r].z = fmaf(av.w, b3.z, acc[r].z); acc[r].w = fmaf(av.w, b3.w, acc[r].w);
    }
  }

  const float4 s4 = reinterpret_cast<const float4*>(a_src)[lane];
  const float4 d4 = reinterpret_cast<const float4*>(a_dst)[lane];
  #pragma unroll
  for (int r = 0; r < 16; ++r) {
    int row = row0 + r;
    if (row < NNODES) {
      *reinterpret_cast<float4*>(H + (size_t)row * DOUT + 4 * lane) = acc[r];
      float ps = acc[r].x * s4.x + acc[r].y * s4.y + acc[r].z * s4.z + acc[r].w * s4.w;
      float pd = acc[r].x * d4.x + acc[r].y * d4.y + acc[r].z * d4.z + acc[r].w * d4.w;
      #pragma unroll
      for (int off = 32; off > 0; off >>= 1) {
        ps += __shfl_xor(ps, off);
        pd += __shfl_xor(pd, off);
      }
      if (lane == 0) { asn[row] = ps; adn[row] = pd; }
    }
  }
}

// ---------------- attention softmax + aggregation ----------------
// one wave per dst node; lane owns 4 output columns.
// MODE 0: out = relu(agg + bias); MODE 1: out = base + relu(agg + bias)
template<int MODE>
__global__ __launch_bounds__(256) void k_agg(
    const float* __restrict__ H, const int* __restrict__ rowptr, const int* __restrict__ esrc,
    const float* __restrict__ asn, const float* __restrict__ adn,
    const float* __restrict__ bias, const float* __restrict__ base, float* __restrict__ out)
{
  const int lane = threadIdx.x & 63;
  const int wv = threadIdx.x >> 6;
  const int n = blockIdx.x * 4 + wv;
  if (n >= NNODES) return;
  const int start = rowptr[n];
  const int end = rowptr[n + 1];
  const float adv = adn[n];

  // segment max
  float m = -1e30f;
  for (int i = start + lane; i < end; i += 64)
    m = fmaxf(m, lrelu(asn[esrc[i]] + adv));
  #pragma unroll
  for (int off = 32; off > 0; off >>= 1) m = fmaxf(m, __shfl_xor(m, off));

  // segment sum of exp
  float s = 0.f;
  for (int i = start + lane; i < end; i += 64)
    s += __expf(lrelu(asn[esrc[i]] + adv) - m);
  #pragma unroll
  for (int off = 32; off > 0; off >>= 1) s += __shfl_xor(s, off);
  const float inv = 1.f / (s + 1e-16f);

  // weighted aggregation
  float4 acc = make_float4(0.f, 0.f, 0.f, 0.f);
  for (int c0 = start; c0 < end; c0 += 64) {
    int i = c0 + lane;
    int msrc = 0;
    float mal = 0.f;
    if (i < end) {
      msrc = esrc[i];
      mal = __expf(lrelu(asn[msrc] + adv) - m) * inv;
    }
    const int cnt = min(64, end - c0);
    for (int j = 0; j < cnt; ++j) {
      const float a = __shfl(mal, j);
      const int sj = __shfl(msrc, j);
      const float4 hv = *reinterpret_cast<const float4*>(H + (size_t)sj * DOUT + 4 * lane);
      acc.x = fmaf(a, hv.x, acc.x);
      acc.y = fmaf(a, hv.y, acc.y);
      acc.z = fmaf(a, hv.z, acc.z);
      acc.w = fmaf(a, hv.w, acc.w);
    }
  }

  const float4 bv = reinterpret_cast<const float4*>(bias)[lane];
  float4 o;
  o.x = fmaxf(acc.x + bv.x, 0.f);
  o.y = fmaxf(acc.y + bv.y, 0.f);
  o.z = fmaxf(acc.z + bv.z, 0.f);
  o.w = fmaxf(acc.w + bv.w, 0.f);
  if (MODE == 1) {
    const float4 r4 = *reinterpret_cast<const float4*>(base + (size_t)n * DOUT + 4 * lane);
    o.x += r4.x; o.y += r4.y; o.z += r4.z; o.w += r4.w;
  }
  *reinterpret_cast<float4*>(out + (size_t)n * DOUT + 4 * lane) = o;
}

// ---------------- launch ----------------
extern "C" void kernel_launch(void* const* d_in, const int* in_sizes, int n_in,
                              void* d_out, int out_size, void* d_ws, size_t ws_size,
                              hipStream_t stream) {
  const float* x   = (const float*)d_in[0];
  const int*   ei  = (const int*)d_in[1];
  const float* W1  = (const float*)d_in[2];
  const float* as1 = (const float*)d_in[3];
  const float* ad1 = (const float*)d_in[4];
  const float* b1  = (const float*)d_in[5];
  const float* W2  = (const float*)d_in[6];
  const float* as2 = (const float*)d_in[7];
  const float* ad2 = (const float*)d_in[8];
  const float* b2  = (const float*)d_in[9];
  const float* W3  = (const float*)d_in[10];
  const float* as3 = (const float*)d_in[11];
  const float* ad3 = (const float*)d_in[12];
  const float* b3  = (const float*)d_in[13];
  float* out = (float*)d_out;

  char* ws = (char*)d_ws;
  size_t off = 0;
  auto alloc = [&](size_t bytes) -> void* {
    void* p = ws + off;
    off = (off + bytes + 255) & ~(size_t)255;
    return p;
  };
  float* X1   = (float*)alloc((size_t)NNODES * DOUT * sizeof(float));
  float* asn  = (float*)alloc(NNODES * sizeof(float));
  float* adn  = (float*)alloc(NNODES * sizeof(float));
  int*   deg  = (int*)alloc(NNODES * sizeof(int));
  int*   rowptr = (int*)alloc((NNODES + 1) * sizeof(int));
  int*   fill = (int*)alloc(NNODES * sizeof(int));
  int*   esrc = (int*)alloc((size_t)(NEDGES + NNODES) * sizeof(int));
  float* HW = out;  // d_out doubles as the per-layer h = A@W buffer

  const int EP = NEDGES + NNODES;
  hipMemsetAsync(deg, 0, NNODES * sizeof(int), stream);
  hipMemsetAsync(fill, 0, NNODES * sizeof(int), stream);
  k_hist<<<(EP + 255) / 256, 256, 0, stream>>>(ei, deg);
  k_scan<<<1, 256, 0, stream>>>(deg, rowptr);
  k_scatter<<<(EP + 255) / 256, 256, 0, stream>>>(ei, rowptr, fill, esrc);

  const int gemmGrid = (NNODES + 63) / 64;
  const int aggGrid  = (NNODES + 3) / 4;

  // layer 1: X1 = relu(gat(x))
  k_gemm_attn<512><<<gemmGrid, 256, 0, stream>>>(x, W1, as1, ad1, HW, asn, adn);
  k_agg<0><<<aggGrid, 256, 0, stream>>>(HW, rowptr, esrc, asn, adn, b1, nullptr, X1);
  // layer 2: X1 = X1 + relu(gat(X1))
  k_gemm_attn<256><<<gemmGrid, 256, 0, stream>>>(X1, W2, as2, ad2, HW, asn, adn);
  k_agg<1><<<aggGrid, 256, 0, stream>>>(HW, rowptr, esrc, asn, adn, b2, X1, X1);
  // layer 3: X1 = X1 + relu(gat(X1)), then copy to d_out
  k_gemm_attn<256><<<gemmGrid, 256, 0, stream>>>(X1, W3, as3, ad3, HW, asn, adn);
  k_agg<1><<<aggGrid, 256, 0, stream>>>(HW, rowptr, esrc, asn, adn, b3, X1, X1);

  hipMemcpyAsync(out, X1, (size_t)NNODES * DOUT * sizeof(float),
                 hipMemcpyDeviceToDevice, stream);
}

// Round 3
// 862.101 us; speedup vs baseline: 1.6001x; 1.6001x over previous
//
#include <hip/hip_runtime.h>
#include <math.h>

#define NNODES 50000
#define NEDGES 1600000
#define DOUT 256
#define NEG_SLOPE 0.2f

typedef __attribute__((ext_vector_type(8))) short short8;
typedef __attribute__((ext_vector_type(4))) float f32x4;

__device__ __forceinline__ float lrelu(float e) { return e > 0.f ? e : NEG_SLOPE * e; }
__device__ __forceinline__ float b2f(unsigned short u) {
  union { unsigned u; float f; } c; c.u = ((unsigned)u) << 16; return c.f;
}
__device__ __forceinline__ unsigned short f2b(float f) {
  union { float f; unsigned u; } c; c.f = f;
  return (unsigned short)((c.u + 0x7fffu + ((c.u >> 16) & 1u)) >> 16);
}

// ---------------- CSR build ----------------
__global__ void k_hist(const int* __restrict__ ei, int* __restrict__ deg) {
  int e = blockIdx.x * 256 + threadIdx.x;
  const int EP = NEDGES + NNODES;
  if (e >= EP) return;
  int dst = (e < NEDGES) ? ei[NEDGES + e] : (e - NEDGES);
  atomicAdd(&deg[dst], 1);
}

__global__ void k_scan(const int* __restrict__ deg, int* __restrict__ rowptr) {
  __shared__ int wsum[4];
  const int t = threadIdx.x, lane = t & 63, w = t >> 6;
  int carry = 0;
  for (int base = 0; base < NNODES; base += 256) {
    int i = base + t;
    int x = (i < NNODES) ? deg[i] : 0;
    #pragma unroll
    for (int off = 1; off < 64; off <<= 1) {
      int y = __shfl_up(x, off);
      if (lane >= off) x += y;
    }
    if (lane == 63) wsum[w] = x;
    __syncthreads();
    int s0 = wsum[0], s1 = wsum[1], s2 = wsum[2], s3 = wsum[3];
    int woff = (w > 0 ? s0 : 0) + (w > 1 ? s1 : 0) + (w > 2 ? s2 : 0);
    if (i < NNODES) rowptr[i + 1] = carry + woff + x;
    carry += s0 + s1 + s2 + s3;
    __syncthreads();
  }
  if (t == 0) rowptr[0] = 0;
}

__global__ void k_scatter(const int* __restrict__ ei, const int* __restrict__ rowptr,
                          int* __restrict__ fill, int* __restrict__ esrc) {
  int e = blockIdx.x * 256 + threadIdx.x;
  const int EP = NEDGES + NNODES;
  if (e >= EP) return;
  int src, dst;
  if (e < NEDGES) { src = ei[e]; dst = ei[NEDGES + e]; }
  else            { src = e - NEDGES; dst = src; }
  int pos = rowptr[dst] + atomicAdd(&fill[dst], 1);
  esrc[pos] = src;
}

// ---------------- casts ----------------
__global__ __launch_bounds__(256) void k_castX(const float4* __restrict__ in,
                                               ushort4* __restrict__ outb, int n4) {
  for (int i = blockIdx.x * 256 + threadIdx.x; i < n4; i += gridDim.x * 256) {
    float4 v = in[i];
    ushort4 o;
    o.x = f2b(v.x); o.y = f2b(v.y); o.z = f2b(v.z); o.w = f2b(v.w);
    outb[i] = o;
  }
}

// W [DIN][DOUT] fp32 -> Wt [DOUT][DIN] bf16
template<int DIN>
__global__ __launch_bounds__(256) void k_castW(const float* __restrict__ W,
                                               unsigned short* __restrict__ Wt) {
  int idx = blockIdx.x * 256 + threadIdx.x;
  if (idx >= DIN * DOUT) return;
  int k = idx / DOUT, n = idx % DOUT;
  Wt[n * DIN + k] = f2b(W[idx]);
}

// ---------------- MFMA GEMM: H = A @ W, + fused attention logits ----------------
// block 256 = 4 waves; block tile 64 rows x 256 cols; wave w owns cols [64w,64w+64)
// A bf16 row-major [M][DIN]; Wt bf16 [DOUT][DIN] (i.e. W transposed)
// Logit partials (per-wave, 64 cols each) are reduced across waves via LDS.
template<int DIN>
__global__ __launch_bounds__(256) void k_gemm_mfma(
    const unsigned short* __restrict__ Ab, const unsigned short* __restrict__ Wt,
    const float* __restrict__ a_src, const float* __restrict__ a_dst,
    unsigned short* __restrict__ Hb, float* __restrict__ asn, float* __restrict__ adn)
{
  __shared__ float s_ps[4][64];
  __shared__ float s_pd[4][64];
  const int lane = threadIdx.x & 63;
  const int wv = threadIdx.x >> 6;
  const int row0 = blockIdx.x * 64;
  const int col0 = wv * 64;
  const int lr = lane & 15;   // A-row / B-col within fragment
  const int lk = lane >> 4;   // k-group (8 elems each)

  f32x4 acc[4][4];
  #pragma unroll
  for (int m = 0; m < 4; ++m)
    #pragma unroll
    for (int n = 0; n < 4; ++n)
      acc[m][n] = (f32x4){0.f, 0.f, 0.f, 0.f};

  const unsigned short* arow[4];
  #pragma unroll
  for (int m = 0; m < 4; ++m) {
    int r = row0 + m * 16 + lr;
    if (r > NNODES - 1) r = NNODES - 1;
    arow[m] = Ab + (size_t)r * DIN + lk * 8;
  }
  const unsigned short* brow[4];
  #pragma unroll
  for (int n = 0; n < 4; ++n)
    brow[n] = Wt + (size_t)(col0 + n * 16 + lr) * DIN + lk * 8;

  for (int k = 0; k < DIN; k += 32) {
    short8 aF[4], bF[4];
    #pragma unroll
    for (int m = 0; m < 4; ++m)
      aF[m] = *reinterpret_cast<const short8*>(arow[m] + k);
    #pragma unroll
    for (int n = 0; n < 4; ++n)
      bF[n] = *reinterpret_cast<const short8*>(brow[n] + k);
    #pragma unroll
    for (int m = 0; m < 4; ++m)
      #pragma unroll
      for (int n = 0; n < 4; ++n)
        acc[m][n] = __builtin_amdgcn_mfma_f32_16x16x32_bf16(aF[m], bF[n], acc[m][n], 0, 0, 0);
  }

  // per-column attention vector entries
  float asv[4], adv[4];
  #pragma unroll
  for (int n = 0; n < 4; ++n) {
    int c = col0 + n * 16 + lr;
    asv[n] = a_src[c];
    adv[n] = a_dst[c];
  }

  #pragma unroll
  for (int m = 0; m < 4; ++m) {
    float ps[4] = {0.f, 0.f, 0.f, 0.f};
    float pd[4] = {0.f, 0.f, 0.f, 0.f};
    #pragma unroll
    for (int n = 0; n < 4; ++n) {
      int col = col0 + n * 16 + lr;
      #pragma unroll
      for (int j = 0; j < 4; ++j) {
        int row = row0 + m * 16 + lk * 4 + j;
        float v = acc[m][n][j];
        if (row < NNODES)
          Hb[(size_t)row * DOUT + col] = f2b(v);
        ps[j] = fmaf(v, asv[n], ps[j]);
        pd[j] = fmaf(v, adv[n], pd[j]);
      }
    }
    // reduce across the 16 lanes sharing this row group (xor of bits 0..3)
    #pragma unroll
    for (int off = 1; off < 16; off <<= 1) {
      #pragma unroll
      for (int j = 0; j < 4; ++j) {
        ps[j] += __shfl_xor(ps[j], off);
        pd[j] += __shfl_xor(pd[j], off);
      }
    }
    if (lr == 0) {
      #pragma unroll
      for (int j = 0; j < 4; ++j) {
        s_ps[wv][m * 16 + lk * 4 + j] = ps[j];
        s_pd[wv][m * 16 + lk * 4 + j] = pd[j];
      }
    }
  }

  // cross-wave reduction: each wave had only 64 of the 256 columns
  __syncthreads();
  const int t = threadIdx.x;
  if (t < 64) {
    int row = row0 + t;
    if (row < NNODES) {
      asn[row] = s_ps[0][t] + s_ps[1][t] + s_ps[2][t] + s_ps[3][t];
      adn[row] = s_pd[0][t] + s_pd[1][t] + s_pd[2][t] + s_pd[3][t];
    }
  }
}

// ---------------- attention softmax + aggregation ----------------
// one wave per dst node; lane owns 4 output columns. H is bf16.
// MODE 0: out = relu(agg + bias); MODE 1: out = base + relu(agg + bias)
// Always also writes bf16 copy of out (next layer's GEMM input).
template<int MODE>
__global__ __launch_bounds__(256) void k_agg(
    const unsigned short* __restrict__ Hb, const int* __restrict__ rowptr,
    const int* __restrict__ esrc, const float* __restrict__ asn,
    const float* __restrict__ adn, const float* __restrict__ bias,
    const float* __restrict__ base, float* __restrict__ out,
    unsigned short* __restrict__ outb)
{
  const int lane = threadIdx.x & 63;
  const int wv = threadIdx.x >> 6;
  const int n = blockIdx.x * 4 + wv;
  if (n >= NNODES) return;
  const int start = rowptr[n];
  const int end = rowptr[n + 1];
  const float adv = adn[n];

  // segment max
  float m = -1e30f;
  for (int i = start + lane; i < end; i += 64)
    m = fmaxf(m, lrelu(asn[esrc[i]] + adv));
  #pragma unroll
  for (int off = 32; off > 0; off >>= 1) m = fmaxf(m, __shfl_xor(m, off));

  // segment sum of exp
  float s = 0.f;
  for (int i = start + lane; i < end; i += 64)
    s += __expf(lrelu(asn[esrc[i]] + adv) - m);
  #pragma unroll
  for (int off = 32; off > 0; off >>= 1) s += __shfl_xor(s, off);
  const float inv = 1.f / (s + 1e-16f);

  // weighted aggregation over bf16 H rows
  float4 acc = make_float4(0.f, 0.f, 0.f, 0.f);
  for (int c0 = start; c0 < end; c0 += 64) {
    int i = c0 + lane;
    int msrc = 0;
    float mal = 0.f;
    if (i < end) {
      msrc = esrc[i];
      mal = __expf(lrelu(asn[msrc] + adv) - m) * inv;
    }
    const int cnt = min(64, end - c0);
    for (int j = 0; j < cnt; ++j) {
      const float a = __shfl(mal, j);
      const int sj = __shfl(msrc, j);
      const ushort4 hv = reinterpret_cast<const ushort4*>(Hb + (size_t)sj * DOUT)[lane];
      acc.x = fmaf(a, b2f(hv.x), acc.x);
      acc.y = fmaf(a, b2f(hv.y), acc.y);
      acc.z = fmaf(a, b2f(hv.z), acc.z);
      acc.w = fmaf(a, b2f(hv.w), acc.w);
    }
  }

  const float4 bv = reinterpret_cast<const float4*>(bias)[lane];
  float4 o;
  o.x = fmaxf(acc.x + bv.x, 0.f);
  o.y = fmaxf(acc.y + bv.y, 0.f);
  o.z = fmaxf(acc.z + bv.z, 0.f);
  o.w = fmaxf(acc.w + bv.w, 0.f);
  if (MODE == 1) {
    const float4 r4 = *reinterpret_cast<const float4*>(base + (size_t)n * DOUT + 4 * lane);
    o.x += r4.x; o.y += r4.y; o.z += r4.z; o.w += r4.w;
  }
  *reinterpret_cast<float4*>(out + (size_t)n * DOUT + 4 * lane) = o;
  ushort4 ob;
  ob.x = f2b(o.x); ob.y = f2b(o.y); ob.z = f2b(o.z); ob.w = f2b(o.w);
  reinterpret_cast<ushort4*>(outb + (size_t)n * DOUT)[lane] = ob;
}

// ---------------- launch ----------------
extern "C" void kernel_launch(void* const* d_in, const int* in_sizes, int n_in,
                              void* d_out, int out_size, void* d_ws, size_t ws_size,
                              hipStream_t stream) {
  const float* x   = (const float*)d_in[0];
  const int*   ei  = (const int*)d_in[1];
  const float* W1  = (const float*)d_in[2];
  const float* as1 = (const float*)d_in[3];
  const float* ad1 = (const float*)d_in[4];
  const float* b1  = (const float*)d_in[5];
  const float* W2  = (const float*)d_in[6];
  const float* as2 = (const float*)d_in[7];
  const float* ad2 = (const float*)d_in[8];
  const float* b2  = (const float*)d_in[9];
  const float* W3  = (const float*)d_in[10];
  const float* as3 = (const float*)d_in[11];
  const float* ad3 = (const float*)d_in[12];
  const float* b3  = (const float*)d_in[13];
  float* out = (float*)d_out;   // doubles as fp32 layer output X1

  char* ws = (char*)d_ws;
  size_t off = 0;
  auto alloc = [&](size_t bytes) -> void* {
    void* p = ws + off;
    off = (off + bytes + 255) & ~(size_t)255;
    return p;
  };
  unsigned short* Xb   = (unsigned short*)alloc((size_t)NNODES * 512 * sizeof(unsigned short)); // layer inputs bf16
  unsigned short* Hb   = (unsigned short*)alloc((size_t)NNODES * DOUT * sizeof(unsigned short));
  unsigned short* W1t  = (unsigned short*)alloc((size_t)512 * DOUT * sizeof(unsigned short));
  unsigned short* W2t  = (unsigned short*)alloc((size_t)DOUT * DOUT * sizeof(unsigned short));
  unsigned short* W3t  = (unsigned short*)alloc((size_t)DOUT * DOUT * sizeof(unsigned short));
  float* asn  = (float*)alloc(NNODES * sizeof(float));
  float* adn  = (float*)alloc(NNODES * sizeof(float));
  int*   deg  = (int*)alloc(NNODES * sizeof(int));
  int*   rowptr = (int*)alloc((NNODES + 1) * sizeof(int));
  int*   fill = (int*)alloc(NNODES * sizeof(int));
  int*   esrc = (int*)alloc((size_t)(NEDGES + NNODES) * sizeof(int));

  const int EP = NEDGES + NNODES;
  hipMemsetAsync(deg, 0, NNODES * sizeof(int), stream);
  hipMemsetAsync(fill, 0, NNODES * sizeof(int), stream);
  k_hist<<<(EP + 255) / 256, 256, 0, stream>>>(ei, deg);
  k_scan<<<1, 256, 0, stream>>>(deg, rowptr);
  k_scatter<<<(EP + 255) / 256, 256, 0, stream>>>(ei, rowptr, fill, esrc);

  // casts
  k_castX<<<2048, 256, 0, stream>>>((const float4*)x, (ushort4*)Xb, NNODES * 512 / 4);
  k_castW<512><<<(512 * DOUT + 255) / 256, 256, 0, stream>>>(W1, W1t);
  k_castW<256><<<(256 * DOUT + 255) / 256, 256, 0, stream>>>(W2, W2t);
  k_castW<256><<<(256 * DOUT + 255) / 256, 256, 0, stream>>>(W3, W3t);

  const int gemmGrid = (NNODES + 63) / 64;
  const int aggGrid  = (NNODES + 3) / 4;

  // layer 1
  k_gemm_mfma<512><<<gemmGrid, 256, 0, stream>>>(Xb, W1t, as1, ad1, Hb, asn, adn);
  k_agg<0><<<aggGrid, 256, 0, stream>>>(Hb, rowptr, esrc, asn, adn, b1, nullptr, out, Xb);
  // layer 2 (Xb now holds bf16 of layer-1 output, 50000x256)
  k_gemm_mfma<256><<<gemmGrid, 256, 0, stream>>>(Xb, W2t, as2, ad2, Hb, asn, adn);
  k_agg<1><<<aggGrid, 256, 0, stream>>>(Hb, rowptr, esrc, asn, adn, b2, out, out, Xb);
  // layer 3
  k_gemm_mfma<256><<<gemmGrid, 256, 0, stream>>>(Xb, W3t, as3, ad3, Hb, asn, adn);
  k_agg<1><<<aggGrid, 256, 0, stream>>>(Hb, rowptr, esrc, asn, adn, b3, out, out, Xb);
}

// Round 5
// 732.329 us; speedup vs baseline: 1.8837x; 1.1772x over previous
//
#include <hip/hip_runtime.h>
#include <math.h>

#define NNODES 50000
#define NEDGES 1600000
#define DOUT 256
#define NEG_SLOPE 0.2f
#define SCANB ((NNODES + 255) / 256)

typedef __attribute__((ext_vector_type(8))) short short8;
typedef __attribute__((ext_vector_type(8))) unsigned short u16x8;
typedef __attribute__((ext_vector_type(4))) float f32x4;

__device__ __forceinline__ float lrelu(float e) { return e > 0.f ? e : NEG_SLOPE * e; }
__device__ __forceinline__ float b2f(unsigned short u) {
  union { unsigned u; float f; } c; c.u = ((unsigned)u) << 16; return c.f;
}
__device__ __forceinline__ unsigned short f2b(float f) {
  union { float f; unsigned u; } c; c.f = f;
  return (unsigned short)((c.u + 0x7fffu + ((c.u >> 16) & 1u)) >> 16);
}

// ---------------- CSR build ----------------
__global__ void k_hist(const int* __restrict__ ei, int* __restrict__ deg) {
  int e = blockIdx.x * 256 + threadIdx.x;
  const int EP = NEDGES + NNODES;
  if (e >= EP) return;
  int dst = (e < NEDGES) ? ei[NEDGES + e] : (e - NEDGES);
  atomicAdd(&deg[dst], 1);
}

// two-level scan: per-block inclusive scan + block totals
__global__ __launch_bounds__(256) void k_scan1(const int* __restrict__ deg,
                                               int* __restrict__ rowptr,
                                               int* __restrict__ bsum) {
  __shared__ int wsum[4];
  const int t = threadIdx.x, lane = t & 63, w = t >> 6;
  const int i = blockIdx.x * 256 + t;
  int x = (i < NNODES) ? deg[i] : 0;
  #pragma unroll
  for (int off = 1; off < 64; off <<= 1) {
    int y = __shfl_up(x, off);
    if (lane >= off) x += y;
  }
  if (lane == 63) wsum[w] = x;
  __syncthreads();
  int s0 = wsum[0], s1 = wsum[1], s2 = wsum[2], s3 = wsum[3];
  int woff = (w > 0 ? s0 : 0) + (w > 1 ? s1 : 0) + (w > 2 ? s2 : 0);
  if (i < NNODES) rowptr[i + 1] = woff + x;
  if (t == 255) bsum[blockIdx.x] = woff + x;
}

__global__ __launch_bounds__(256) void k_scan2(int* __restrict__ bsum,
                                               int* __restrict__ bexcl) {
  __shared__ int wsum[4];
  const int t = threadIdx.x, lane = t & 63, w = t >> 6;
  int v = (t < SCANB) ? bsum[t] : 0;
  int x = v;
  #pragma unroll
  for (int off = 1; off < 64; off <<= 1) {
    int y = __shfl_up(x, off);
    if (lane >= off) x += y;
  }
  if (lane == 63) wsum[w] = x;
  __syncthreads();
  int s0 = wsum[0], s1 = wsum[1], s2 = wsum[2], s3 = wsum[3];
  int woff = (w > 0 ? s0 : 0) + (w > 1 ? s1 : 0) + (w > 2 ? s2 : 0);
  if (t < SCANB) bexcl[t] = woff + x - v;
}

__global__ __launch_bounds__(256) void k_scan3(int* __restrict__ rowptr,
                                               const int* __restrict__ bexcl) {
  const int i = blockIdx.x * 256 + threadIdx.x;
  if (i == 0) rowptr[0] = 0;
  if (i < NNODES) rowptr[i + 1] += bexcl[blockIdx.x];
}

__global__ void k_scatter(const int* __restrict__ ei, const int* __restrict__ rowptr,
                          int* __restrict__ fill, int* __restrict__ esrc) {
  int e = blockIdx.x * 256 + threadIdx.x;
  const int EP = NEDGES + NNODES;
  if (e >= EP) return;
  int src, dst;
  if (e < NEDGES) { src = ei[e]; dst = ei[NEDGES + e]; }
  else            { src = e - NEDGES; dst = src; }
  int pos = rowptr[dst] + atomicAdd(&fill[dst], 1);
  esrc[pos] = src;
}

// ---------------- casts ----------------
__global__ __launch_bounds__(256) void k_castX(const float4* __restrict__ in,
                                               ushort4* __restrict__ outb, int n4) {
  for (int i = blockIdx.x * 256 + threadIdx.x; i < n4; i += gridDim.x * 256) {
    float4 v = in[i];
    ushort4 o;
    o.x = f2b(v.x); o.y = f2b(v.y); o.z = f2b(v.z); o.w = f2b(v.w);
    outb[i] = o;
  }
}

// W [DIN][DOUT] fp32 -> Wt [DOUT][DIN] bf16
template<int DIN>
__global__ __launch_bounds__(256) void k_castW(const float* __restrict__ W,
                                               unsigned short* __restrict__ Wt) {
  int idx = blockIdx.x * 256 + threadIdx.x;
  if (idx >= DIN * DOUT) return;
  int k = idx / DOUT, n = idx % DOUT;
  Wt[n * DIN + k] = f2b(W[idx]);
}

// ---------------- MFMA GEMM: H = A @ W, + fused attention logits ----------------
template<int DIN>
__global__ __launch_bounds__(256) void k_gemm_mfma(
    const unsigned short* __restrict__ Ab, const unsigned short* __restrict__ Wt,
    const float* __restrict__ a_src, const float* __restrict__ a_dst,
    unsigned short* __restrict__ Hb, float* __restrict__ asn, float* __restrict__ adn)
{
  __shared__ float s_ps[4][64];
  __shared__ float s_pd[4][64];
  const int lane = threadIdx.x & 63;
  const int wv = threadIdx.x >> 6;
  const int row0 = blockIdx.x * 64;
  const int col0 = wv * 64;
  const int lr = lane & 15;
  const int lk = lane >> 4;

  f32x4 acc[4][4];
  #pragma unroll
  for (int m = 0; m < 4; ++m)
    #pragma unroll
    for (int n = 0; n < 4; ++n)
      acc[m][n] = (f32x4){0.f, 0.f, 0.f, 0.f};

  const unsigned short* arow[4];
  #pragma unroll
  for (int m = 0; m < 4; ++m) {
    int r = row0 + m * 16 + lr;
    if (r > NNODES - 1) r = NNODES - 1;
    arow[m] = Ab + (size_t)r * DIN + lk * 8;
  }
  const unsigned short* brow[4];
  #pragma unroll
  for (int n = 0; n < 4; ++n)
    brow[n] = Wt + (size_t)(col0 + n * 16 + lr) * DIN + lk * 8;

  for (int k = 0; k < DIN; k += 32) {
    short8 aF[4], bF[4];
    #pragma unroll
    for (int m = 0; m < 4; ++m)
      aF[m] = *reinterpret_cast<const short8*>(arow[m] + k);
    #pragma unroll
    for (int n = 0; n < 4; ++n)
      bF[n] = *reinterpret_cast<const short8*>(brow[n] + k);
    #pragma unroll
    for (int m = 0; m < 4; ++m)
      #pragma unroll
      for (int n = 0; n < 4; ++n)
        acc[m][n] = __builtin_amdgcn_mfma_f32_16x16x32_bf16(aF[m], bF[n], acc[m][n], 0, 0, 0);
  }

  float asv[4], adv[4];
  #pragma unroll
  for (int n = 0; n < 4; ++n) {
    int c = col0 + n * 16 + lr;
    asv[n] = a_src[c];
    adv[n] = a_dst[c];
  }

  #pragma unroll
  for (int m = 0; m < 4; ++m) {
    float ps[4] = {0.f, 0.f, 0.f, 0.f};
    float pd[4] = {0.f, 0.f, 0.f, 0.f};
    #pragma unroll
    for (int n = 0; n < 4; ++n) {
      int col = col0 + n * 16 + lr;
      #pragma unroll
      for (int j = 0; j < 4; ++j) {
        int row = row0 + m * 16 + lk * 4 + j;
        float v = acc[m][n][j];
        if (row < NNODES)
          Hb[(size_t)row * DOUT + col] = f2b(v);
        ps[j] = fmaf(v, asv[n], ps[j]);
        pd[j] = fmaf(v, adv[n], pd[j]);
      }
    }
    #pragma unroll
    for (int off = 1; off < 16; off <<= 1) {
      #pragma unroll
      for (int j = 0; j < 4; ++j) {
        ps[j] += __shfl_xor(ps[j], off);
        pd[j] += __shfl_xor(pd[j], off);
      }
    }
    if (lr == 0) {
      #pragma unroll
      for (int j = 0; j < 4; ++j) {
        s_ps[wv][m * 16 + lk * 4 + j] = ps[j];
        s_pd[wv][m * 16 + lk * 4 + j] = pd[j];
      }
    }
  }

  __syncthreads();
  const int t = threadIdx.x;
  if (t < 64) {
    int row = row0 + t;
    if (row < NNODES) {
      asn[row] = s_ps[0][t] + s_ps[1][t] + s_ps[2][t] + s_ps[3][t];
      adn[row] = s_pd[0][t] + s_pd[1][t] + s_pd[2][t] + s_pd[3][t];
    }
  }
}

// ---------------- attention softmax + aggregation ----------------
// one wave per dst node; 2 edges per step with a WAVE-UNIFORM trip count:
// lanes 0-31 take even edges, 32-63 odd edges; the odd half's out-of-range
// final selector is clamped to a valid lane and its weight forced to 0.
// No divergent control flow around the shfls.
template<int MODE>
__global__ __launch_bounds__(256) void k_agg(
    const unsigned short* __restrict__ Hb, const int* __restrict__ rowptr,
    const int* __restrict__ esrc, const float* __restrict__ asn,
    const float* __restrict__ adn, const float* __restrict__ bias,
    const float* __restrict__ base, float* __restrict__ out,
    unsigned short* __restrict__ outb)
{
  const int lane = threadIdx.x & 63;
  const int wv = threadIdx.x >> 6;
  const int n = blockIdx.x * 4 + wv;
  if (n >= NNODES) return;
  const int start = rowptr[n];
  const int end = rowptr[n + 1];
  const float adv = adn[n];

  // segment max
  float m = -1e30f;
  for (int i = start + lane; i < end; i += 64)
    m = fmaxf(m, lrelu(asn[esrc[i]] + adv));
  #pragma unroll
  for (int off = 32; off > 0; off >>= 1) m = fmaxf(m, __shfl_xor(m, off));

  // segment sum of exp
  float s = 0.f;
  for (int i = start + lane; i < end; i += 64)
    s += __expf(lrelu(asn[esrc[i]] + adv) - m);
  #pragma unroll
  for (int off = 32; off > 0; off >>= 1) s += __shfl_xor(s, off);
  const float inv = 1.f / (s + 1e-16f);

  // weighted aggregation: 2 edges per step, 16B gathers, uniform trip count
  const int half = lane >> 5;       // which edge of the pair
  const int c8 = lane & 31;         // col-group [c8*8, c8*8+8)
  float acc[8];
  #pragma unroll
  for (int k = 0; k < 8; ++k) acc[k] = 0.f;

  for (int c0 = start; c0 < end; c0 += 64) {
    int i = c0 + lane;
    int msrc = 0;
    float mal = 0.f;
    if (i < end) {
      msrc = esrc[i];
      mal = __expf(lrelu(asn[msrc] + adv) - m) * inv;
    }
    const int cnt = min(64, end - c0);
    const int pcnt = (cnt + 1) >> 1;          // uniform across the wave
    for (int jj = 0; jj < pcnt; ++jj) {
      const int esel = 2 * jj + half;          // may be == cnt (odd half, odd cnt)
      const int esafe = (esel < cnt) ? esel : 0;
      float a = __shfl(mal, esafe);
      const int sj = __shfl(msrc, esafe);
      if (esel >= cnt) a = 0.f;                // kill the duplicate
      const u16x8 hv = *reinterpret_cast<const u16x8*>(Hb + (size_t)sj * DOUT + c8 * 8);
      #pragma unroll
      for (int k = 0; k < 8; ++k)
        acc[k] = fmaf(a, b2f((unsigned short)hv[k]), acc[k]);
    }
  }
  // combine even/odd halves
  #pragma unroll
  for (int k = 0; k < 8; ++k) acc[k] += __shfl_xor(acc[k], 32);

  if (half == 0) {
    float o[8];
    #pragma unroll
    for (int k = 0; k < 8; ++k) o[k] = fmaxf(acc[k] + bias[c8 * 8 + k], 0.f);
    if (MODE == 1) {
      const float4 r0 = *reinterpret_cast<const float4*>(base + (size_t)n * DOUT + c8 * 8);
      const float4 r1 = *reinterpret_cast<const float4*>(base + (size_t)n * DOUT + c8 * 8 + 4);
      o[0] += r0.x; o[1] += r0.y; o[2] += r0.z; o[3] += r0.w;
      o[4] += r1.x; o[5] += r1.y; o[6] += r1.z; o[7] += r1.w;
    }
    float4 o0 = make_float4(o[0], o[1], o[2], o[3]);
    float4 o1 = make_float4(o[4], o[5], o[6], o[7]);
    *reinterpret_cast<float4*>(out + (size_t)n * DOUT + c8 * 8) = o0;
    *reinterpret_cast<float4*>(out + (size_t)n * DOUT + c8 * 8 + 4) = o1;
    u16x8 ob;
    #pragma unroll
    for (int k = 0; k < 8; ++k) ob[k] = f2b(o[k]);
    *reinterpret_cast<u16x8*>(outb + (size_t)n * DOUT + c8 * 8) = ob;
  }
}

// ---------------- launch ----------------
extern "C" void kernel_launch(void* const* d_in, const int* in_sizes, int n_in,
                              void* d_out, int out_size, void* d_ws, size_t ws_size,
                              hipStream_t stream) {
  const float* x   = (const float*)d_in[0];
  const int*   ei  = (const int*)d_in[1];
  const float* W1  = (const float*)d_in[2];
  const float* as1 = (const float*)d_in[3];
  const float* ad1 = (const float*)d_in[4];
  const float* b1  = (const float*)d_in[5];
  const float* W2  = (const float*)d_in[6];
  const float* as2 = (const float*)d_in[7];
  const float* ad2 = (const float*)d_in[8];
  const float* b2  = (const float*)d_in[9];
  const float* W3  = (const float*)d_in[10];
  const float* as3 = (const float*)d_in[11];
  const float* ad3 = (const float*)d_in[12];
  const float* b3  = (const float*)d_in[13];
  float* out = (float*)d_out;   // doubles as fp32 layer output X1

  char* ws = (char*)d_ws;
  size_t off = 0;
  auto alloc = [&](size_t bytes) -> void* {
    void* p = ws + off;
    off = (off + bytes + 255) & ~(size_t)255;
    return p;
  };
  unsigned short* Xb   = (unsigned short*)alloc((size_t)NNODES * 512 * sizeof(unsigned short));
  unsigned short* Hb   = (unsigned short*)alloc((size_t)NNODES * DOUT * sizeof(unsigned short));
  unsigned short* W1t  = (unsigned short*)alloc((size_t)512 * DOUT * sizeof(unsigned short));
  unsigned short* W2t  = (unsigned short*)alloc((size_t)DOUT * DOUT * sizeof(unsigned short));
  unsigned short* W3t  = (unsigned short*)alloc((size_t)DOUT * DOUT * sizeof(unsigned short));
  float* asn  = (float*)alloc(NNODES * sizeof(float));
  float* adn  = (float*)alloc(NNODES * sizeof(float));
  int*   deg  = (int*)alloc(NNODES * sizeof(int));
  int*   rowptr = (int*)alloc((NNODES + 1) * sizeof(int));
  int*   fill = (int*)alloc(NNODES * sizeof(int));
  int*   bsum = (int*)alloc(SCANB * sizeof(int));
  int*   bexcl = (int*)alloc(SCANB * sizeof(int));
  int*   esrc = (int*)alloc((size_t)(NEDGES + NNODES) * sizeof(int));

  const int EP = NEDGES + NNODES;
  hipMemsetAsync(deg, 0, NNODES * sizeof(int), stream);
  hipMemsetAsync(fill, 0, NNODES * sizeof(int), stream);
  k_hist<<<(EP + 255) / 256, 256, 0, stream>>>(ei, deg);
  k_scan1<<<SCANB, 256, 0, stream>>>(deg, rowptr, bsum);
  k_scan2<<<1, 256, 0, stream>>>(bsum, bexcl);
  k_scan3<<<SCANB, 256, 0, stream>>>(rowptr, bexcl);
  k_scatter<<<(EP + 255) / 256, 256, 0, stream>>>(ei, rowptr, fill, esrc);

  // casts
  k_castX<<<2048, 256, 0, stream>>>((const float4*)x, (ushort4*)Xb, NNODES * 512 / 4);
  k_castW<512><<<(512 * DOUT + 255) / 256, 256, 0, stream>>>(W1, W1t);
  k_castW<256><<<(256 * DOUT + 255) / 256, 256, 0, stream>>>(W2, W2t);
  k_castW<256><<<(256 * DOUT + 255) / 256, 256, 0, stream>>>(W3, W3t);

  const int gemmGrid = (NNODES + 63) / 64;
  const int aggGrid  = (NNODES + 3) / 4;

  // layer 1
  k_gemm_mfma<512><<<gemmGrid, 256, 0, stream>>>(Xb, W1t, as1, ad1, Hb, asn, adn);
  k_agg<0><<<aggGrid, 256, 0, stream>>>(Hb, rowptr, esrc, asn, adn, b1, nullptr, out, Xb);
  // layer 2
  k_gemm_mfma<256><<<gemmGrid, 256, 0, stream>>>(Xb, W2t, as2, ad2, Hb, asn, adn);
  k_agg<1><<<aggGrid, 256, 0, stream>>>(Hb, rowptr, esrc, asn, adn, b2, out, out, Xb);
  // layer 3
  k_gemm_mfma<256><<<gemmGrid, 256, 0, stream>>>(Xb, W3t, as3, ad3, Hb, asn, adn);
  k_agg<1><<<aggGrid, 256, 0, stream>>>(Hb, rowptr, esrc, asn, adn, b3, out, out, Xb);
}

// Round 6
// 696.871 us; speedup vs baseline: 1.9795x; 1.0509x over previous
//
#include <hip/hip_runtime.h>
#include <math.h>

#define NNODES 50000
#define NEDGES 1600000
#define DOUT 256
#define NEG_SLOPE 0.2f
#define SCANB ((NNODES + 255) / 256)

typedef __attribute__((ext_vector_type(8))) short short8;
typedef __attribute__((ext_vector_type(8))) unsigned short u16x8;
typedef __attribute__((ext_vector_type(4))) float f32x4;

__device__ __forceinline__ float lrelu(float e) { return e > 0.f ? e : NEG_SLOPE * e; }
__device__ __forceinline__ float b2f(unsigned short u) {
  union { unsigned u; float f; } c; c.u = ((unsigned)u) << 16; return c.f;
}
__device__ __forceinline__ unsigned short f2b(float f) {
  union { float f; unsigned u; } c; c.f = f;
  return (unsigned short)((c.u + 0x7fffu + ((c.u >> 16) & 1u)) >> 16);
}

// ---------------- CSR build ----------------
__global__ void k_hist(const int* __restrict__ ei, int* __restrict__ deg) {
  int e = blockIdx.x * 256 + threadIdx.x;
  const int EP = NEDGES + NNODES;
  if (e >= EP) return;
  int dst = (e < NEDGES) ? ei[NEDGES + e] : (e - NEDGES);
  atomicAdd(&deg[dst], 1);
}

// two-level scan: per-block inclusive scan + block totals
__global__ __launch_bounds__(256) void k_scan1(const int* __restrict__ deg,
                                               int* __restrict__ rowptr,
                                               int* __restrict__ bsum) {
  __shared__ int wsum[4];
  const int t = threadIdx.x, lane = t & 63, w = t >> 6;
  const int i = blockIdx.x * 256 + t;
  int x = (i < NNODES) ? deg[i] : 0;
  #pragma unroll
  for (int off = 1; off < 64; off <<= 1) {
    int y = __shfl_up(x, off);
    if (lane >= off) x += y;
  }
  if (lane == 63) wsum[w] = x;
  __syncthreads();
  int s0 = wsum[0], s1 = wsum[1], s2 = wsum[2], s3 = wsum[3];
  int woff = (w > 0 ? s0 : 0) + (w > 1 ? s1 : 0) + (w > 2 ? s2 : 0);
  if (i < NNODES) rowptr[i + 1] = woff + x;
  if (t == 255) bsum[blockIdx.x] = woff + x;
}

__global__ __launch_bounds__(256) void k_scan2(int* __restrict__ bsum,
                                               int* __restrict__ bexcl) {
  __shared__ int wsum[4];
  const int t = threadIdx.x, lane = t & 63, w = t >> 6;
  int v = (t < SCANB) ? bsum[t] : 0;
  int x = v;
  #pragma unroll
  for (int off = 1; off < 64; off <<= 1) {
    int y = __shfl_up(x, off);
    if (lane >= off) x += y;
  }
  if (lane == 63) wsum[w] = x;
  __syncthreads();
  int s0 = wsum[0], s1 = wsum[1], s2 = wsum[2], s3 = wsum[3];
  int woff = (w > 0 ? s0 : 0) + (w > 1 ? s1 : 0) + (w > 2 ? s2 : 0);
  if (t < SCANB) bexcl[t] = woff + x - v;
}

__global__ __launch_bounds__(256) void k_scan3(int* __restrict__ rowptr,
                                               const int* __restrict__ bexcl) {
  const int i = blockIdx.x * 256 + threadIdx.x;
  if (i == 0) rowptr[0] = 0;
  if (i < NNODES) rowptr[i + 1] += bexcl[blockIdx.x];
}

__global__ void k_scatter(const int* __restrict__ ei, const int* __restrict__ rowptr,
                          int* __restrict__ fill, int* __restrict__ esrc) {
  int e = blockIdx.x * 256 + threadIdx.x;
  const int EP = NEDGES + NNODES;
  if (e >= EP) return;
  int src, dst;
  if (e < NEDGES) { src = ei[e]; dst = ei[NEDGES + e]; }
  else            { src = e - NEDGES; dst = src; }
  int pos = rowptr[dst] + atomicAdd(&fill[dst], 1);
  esrc[pos] = src;
}

// ---------------- casts ----------------
__global__ __launch_bounds__(256) void k_castX(const float4* __restrict__ in,
                                               ushort4* __restrict__ outb, int n4) {
  for (int i = blockIdx.x * 256 + threadIdx.x; i < n4; i += gridDim.x * 256) {
    float4 v = in[i];
    ushort4 o;
    o.x = f2b(v.x); o.y = f2b(v.y); o.z = f2b(v.z); o.w = f2b(v.w);
    outb[i] = o;
  }
}

// W [DIN][DOUT] fp32 -> Wt [DOUT][DIN] bf16
template<int DIN>
__global__ __launch_bounds__(256) void k_castW(const float* __restrict__ W,
                                               unsigned short* __restrict__ Wt) {
  int idx = blockIdx.x * 256 + threadIdx.x;
  if (idx >= DIN * DOUT) return;
  int k = idx / DOUT, n = idx % DOUT;
  Wt[n * DIN + k] = f2b(W[idx]);
}

// ---------------- MFMA GEMM: H = A @ W, + fused attention logits ----------------
template<int DIN>
__global__ __launch_bounds__(256) void k_gemm_mfma(
    const unsigned short* __restrict__ Ab, const unsigned short* __restrict__ Wt,
    const float* __restrict__ a_src, const float* __restrict__ a_dst,
    unsigned short* __restrict__ Hb, float* __restrict__ asn, float* __restrict__ adn)
{
  __shared__ float s_ps[4][64];
  __shared__ float s_pd[4][64];
  const int lane = threadIdx.x & 63;
  const int wv = threadIdx.x >> 6;
  const int row0 = blockIdx.x * 64;
  const int col0 = wv * 64;
  const int lr = lane & 15;
  const int lk = lane >> 4;

  f32x4 acc[4][4];
  #pragma unroll
  for (int m = 0; m < 4; ++m)
    #pragma unroll
    for (int n = 0; n < 4; ++n)
      acc[m][n] = (f32x4){0.f, 0.f, 0.f, 0.f};

  const unsigned short* arow[4];
  #pragma unroll
  for (int m = 0; m < 4; ++m) {
    int r = row0 + m * 16 + lr;
    if (r > NNODES - 1) r = NNODES - 1;
    arow[m] = Ab + (size_t)r * DIN + lk * 8;
  }
  const unsigned short* brow[4];
  #pragma unroll
  for (int n = 0; n < 4; ++n)
    brow[n] = Wt + (size_t)(col0 + n * 16 + lr) * DIN + lk * 8;

  for (int k = 0; k < DIN; k += 32) {
    short8 aF[4], bF[4];
    #pragma unroll
    for (int m = 0; m < 4; ++m)
      aF[m] = *reinterpret_cast<const short8*>(arow[m] + k);
    #pragma unroll
    for (int n = 0; n < 4; ++n)
      bF[n] = *reinterpret_cast<const short8*>(brow[n] + k);
    #pragma unroll
    for (int m = 0; m < 4; ++m)
      #pragma unroll
      for (int n = 0; n < 4; ++n)
        acc[m][n] = __builtin_amdgcn_mfma_f32_16x16x32_bf16(aF[m], bF[n], acc[m][n], 0, 0, 0);
  }

  float asv[4], adv[4];
  #pragma unroll
  for (int n = 0; n < 4; ++n) {
    int c = col0 + n * 16 + lr;
    asv[n] = a_src[c];
    adv[n] = a_dst[c];
  }

  #pragma unroll
  for (int m = 0; m < 4; ++m) {
    float ps[4] = {0.f, 0.f, 0.f, 0.f};
    float pd[4] = {0.f, 0.f, 0.f, 0.f};
    #pragma unroll
    for (int n = 0; n < 4; ++n) {
      int col = col0 + n * 16 + lr;
      #pragma unroll
      for (int j = 0; j < 4; ++j) {
        int row = row0 + m * 16 + lk * 4 + j;
        float v = acc[m][n][j];
        if (row < NNODES)
          Hb[(size_t)row * DOUT + col] = f2b(v);
        ps[j] = fmaf(v, asv[n], ps[j]);
        pd[j] = fmaf(v, adv[n], pd[j]);
      }
    }
    #pragma unroll
    for (int off = 1; off < 16; off <<= 1) {
      #pragma unroll
      for (int j = 0; j < 4; ++j) {
        ps[j] += __shfl_xor(ps[j], off);
        pd[j] += __shfl_xor(pd[j], off);
      }
    }
    if (lr == 0) {
      #pragma unroll
      for (int j = 0; j < 4; ++j) {
        s_ps[wv][m * 16 + lk * 4 + j] = ps[j];
        s_pd[wv][m * 16 + lk * 4 + j] = pd[j];
      }
    }
  }

  __syncthreads();
  const int t = threadIdx.x;
  if (t < 64) {
    int row = row0 + t;
    if (row < NNODES) {
      asn[row] = s_ps[0][t] + s_ps[1][t] + s_ps[2][t] + s_ps[3][t];
      adn[row] = s_pd[0][t] + s_pd[1][t] + s_pd[2][t] + s_pd[3][t];
    }
  }
}

// ---------------- attention softmax + aggregation ----------------
// one wave per dst node.
// Pass 1 (fused): online-softmax running (m, s) per lane, merged butterfly.
// Pass 2: 2 edges per step, unrolled x2 (4 edges / 2KB gather in flight).
template<int MODE>
__global__ __launch_bounds__(256) void k_agg(
    const unsigned short* __restrict__ Hb, const int* __restrict__ rowptr,
    const int* __restrict__ esrc, const float* __restrict__ asn,
    const float* __restrict__ adn, const float* __restrict__ bias,
    const float* __restrict__ base, float* __restrict__ out,
    unsigned short* __restrict__ outb)
{
  const int lane = threadIdx.x & 63;
  const int wv = threadIdx.x >> 6;
  const int n = blockIdx.x * 4 + wv;
  if (n >= NNODES) return;
  const int start = rowptr[n];
  const int end = rowptr[n + 1];
  const float adv = adn[n];

  // fused online segment max + exp-sum
  float m = -1e30f;
  float s = 0.f;
  for (int i = start + lane; i < end; i += 64) {
    float e = lrelu(asn[esrc[i]] + adv);
    float mn = fmaxf(m, e);
    s = s * __expf(m - mn) + __expf(e - mn);
    m = mn;
  }
  #pragma unroll
  for (int off = 32; off > 0; off >>= 1) {
    float mo = __shfl_xor(m, off);
    float so = __shfl_xor(s, off);
    float mn = fmaxf(m, mo);
    s = s * __expf(m - mn) + so * __expf(mo - mn);
    m = mn;
  }
  const float inv = 1.f / (s + 1e-16f);

  // weighted aggregation: 2 edges per step, unrolled x2, uniform trip count
  const int half = lane >> 5;       // which edge of the pair
  const int c8 = lane & 31;         // col-group [c8*8, c8*8+8)
  float acc[8];
  #pragma unroll
  for (int k = 0; k < 8; ++k) acc[k] = 0.f;

  for (int c0 = start; c0 < end; c0 += 64) {
    int i = c0 + lane;
    int msrc = 0;
    float mal = 0.f;
    if (i < end) {
      msrc = esrc[i];
      mal = __expf(lrelu(asn[msrc] + adv) - m) * inv;
    }
    const int cnt = min(64, end - c0);
    const int pcnt = (cnt + 1) >> 1;          // uniform across the wave
    for (int jj = 0; jj < pcnt; jj += 2) {
      const int e0 = 2 * jj + half;
      const int e1 = e0 + 2;
      const int s0 = (e0 < cnt) ? e0 : 0;
      const int s1 = (e1 < cnt) ? e1 : 0;
      const bool v1ok = (jj + 1 < pcnt);
      float a0 = __shfl(mal, s0);
      const int sj0 = __shfl(msrc, s0);
      float a1 = __shfl(mal, s1);
      const int sj1 = __shfl(msrc, s1);
      if (e0 >= cnt) a0 = 0.f;
      if (!v1ok || e1 >= cnt) a1 = 0.f;
      const u16x8 hv0 = *reinterpret_cast<const u16x8*>(Hb + (size_t)sj0 * DOUT + c8 * 8);
      const u16x8 hv1 = *reinterpret_cast<const u16x8*>(Hb + (size_t)sj1 * DOUT + c8 * 8);
      #pragma unroll
      for (int k = 0; k < 8; ++k)
        acc[k] = fmaf(a0, b2f((unsigned short)hv0[k]), acc[k]);
      #pragma unroll
      for (int k = 0; k < 8; ++k)
        acc[k] = fmaf(a1, b2f((unsigned short)hv1[k]), acc[k]);
    }
  }
  // combine even/odd halves
  #pragma unroll
  for (int k = 0; k < 8; ++k) acc[k] += __shfl_xor(acc[k], 32);

  if (half == 0) {
    float o[8];
    #pragma unroll
    for (int k = 0; k < 8; ++k) o[k] = fmaxf(acc[k] + bias[c8 * 8 + k], 0.f);
    if (MODE == 1) {
      const float4 r0 = *reinterpret_cast<const float4*>(base + (size_t)n * DOUT + c8 * 8);
      const float4 r1 = *reinterpret_cast<const float4*>(base + (size_t)n * DOUT + c8 * 8 + 4);
      o[0] += r0.x; o[1] += r0.y; o[2] += r0.z; o[3] += r0.w;
      o[4] += r1.x; o[5] += r1.y; o[6] += r1.z; o[7] += r1.w;
    }
    float4 o0 = make_float4(o[0], o[1], o[2], o[3]);
    float4 o1 = make_float4(o[4], o[5], o[6], o[7]);
    *reinterpret_cast<float4*>(out + (size_t)n * DOUT + c8 * 8) = o0;
    *reinterpret_cast<float4*>(out + (size_t)n * DOUT + c8 * 8 + 4) = o1;
    u16x8 ob;
    #pragma unroll
    for (int k = 0; k < 8; ++k) ob[k] = f2b(o[k]);
    *reinterpret_cast<u16x8*>(outb + (size_t)n * DOUT + c8 * 8) = ob;
  }
}

// ---------------- launch ----------------
extern "C" void kernel_launch(void* const* d_in, const int* in_sizes, int n_in,
                              void* d_out, int out_size, void* d_ws, size_t ws_size,
                              hipStream_t stream) {
  const float* x   = (const float*)d_in[0];
  const int*   ei  = (const int*)d_in[1];
  const float* W1  = (const float*)d_in[2];
  const float* as1 = (const float*)d_in[3];
  const float* ad1 = (const float*)d_in[4];
  const float* b1  = (const float*)d_in[5];
  const float* W2  = (const float*)d_in[6];
  const float* as2 = (const float*)d_in[7];
  const float* ad2 = (const float*)d_in[8];
  const float* b2  = (const float*)d_in[9];
  const float* W3  = (const float*)d_in[10];
  const float* as3 = (const float*)d_in[11];
  const float* ad3 = (const float*)d_in[12];
  const float* b3  = (const float*)d_in[13];
  float* out = (float*)d_out;   // doubles as fp32 layer output X1

  char* ws = (char*)d_ws;
  size_t off = 0;
  auto alloc = [&](size_t bytes) -> void* {
    void* p = ws + off;
    off = (off + bytes + 255) & ~(size_t)255;
    return p;
  };
  unsigned short* Xb   = (unsigned short*)alloc((size_t)NNODES * 512 * sizeof(unsigned short));
  unsigned short* Hb   = (unsigned short*)alloc((size_t)NNODES * DOUT * sizeof(unsigned short));
  unsigned short* W1t  = (unsigned short*)alloc((size_t)512 * DOUT * sizeof(unsigned short));
  unsigned short* W2t  = (unsigned short*)alloc((size_t)DOUT * DOUT * sizeof(unsigned short));
  unsigned short* W3t  = (unsigned short*)alloc((size_t)DOUT * DOUT * sizeof(unsigned short));
  float* asn  = (float*)alloc(NNODES * sizeof(float));
  float* adn  = (float*)alloc(NNODES * sizeof(float));
  int*   deg  = (int*)alloc(NNODES * sizeof(int));
  int*   rowptr = (int*)alloc((NNODES + 1) * sizeof(int));
  int*   fill = (int*)alloc(NNODES * sizeof(int));
  int*   bsum = (int*)alloc(SCANB * sizeof(int));
  int*   bexcl = (int*)alloc(SCANB * sizeof(int));
  int*   esrc = (int*)alloc((size_t)(NEDGES + NNODES) * sizeof(int));

  const int EP = NEDGES + NNODES;
  hipMemsetAsync(deg, 0, NNODES * sizeof(int), stream);
  hipMemsetAsync(fill, 0, NNODES * sizeof(int), stream);
  k_hist<<<(EP + 255) / 256, 256, 0, stream>>>(ei, deg);
  k_scan1<<<SCANB, 256, 0, stream>>>(deg, rowptr, bsum);
  k_scan2<<<1, 256, 0, stream>>>(bsum, bexcl);
  k_scan3<<<SCANB, 256, 0, stream>>>(rowptr, bexcl);
  k_scatter<<<(EP + 255) / 256, 256, 0, stream>>>(ei, rowptr, fill, esrc);

  // casts
  k_castX<<<2048, 256, 0, stream>>>((const float4*)x, (ushort4*)Xb, NNODES * 512 / 4);
  k_castW<512><<<(512 * DOUT + 255) / 256, 256, 0, stream>>>(W1, W1t);
  k_castW<256><<<(256 * DOUT + 255) / 256, 256, 0, stream>>>(W2, W2t);
  k_castW<256><<<(256 * DOUT + 255) / 256, 256, 0, stream>>>(W3, W3t);

  const int gemmGrid = (NNODES + 63) / 64;
  const int aggGrid  = (NNODES + 3) / 4;

  // layer 1
  k_gemm_mfma<512><<<gemmGrid, 256, 0, stream>>>(Xb, W1t, as1, ad1, Hb, asn, adn);
  k_agg<0><<<aggGrid, 256, 0, stream>>>(Hb, rowptr, esrc, asn, adn, b1, nullptr, out, Xb);
  // layer 2
  k_gemm_mfma<256><<<gemmGrid, 256, 0, stream>>>(Xb, W2t, as2, ad2, Hb, asn, adn);
  k_agg<1><<<aggGrid, 256, 0, stream>>>(Hb, rowptr, esrc, asn, adn, b2, out, out, Xb);
  // layer 3
  k_gemm_mfma<256><<<gemmGrid, 256, 0, stream>>>(Xb, W3t, as3, ad3, Hb, asn, adn);
  k_agg<1><<<aggGrid, 256, 0, stream>>>(Hb, rowptr, esrc, asn, adn, b3, out, out, Xb);
}